// Round 1
// 676.385 us; speedup vs baseline: 1.0541x; 1.0541x over previous
//
#include <hip/hip_runtime.h>
#include <math.h>

#define NN 27
#define HID 128
#define SITERS 20
#define H1S 136          // f16 row stride for h1/H in LDS (272 B = 16B-aligned, bank-spread)

typedef float    v4    __attribute__((ext_vector_type(4)));
typedef _Float16 f16x8 __attribute__((ext_vector_type(8)));

// ---------------- Kernel 0: pre-swizzle W2 / protos into f16 MFMA fragment order ----------------
// B-frag (16x16x32): lane l holds B[k=kt*32+(l>>4)*8+j][n=nt*16+(l&15)], j=0..7 -> one 16B load/lane.
// A-frag:            lane l holds A[m=mt*16+(l&15)][k=kt*32+(l>>4)*8+j]          (m120-verified layout)
__global__ void k0_prep(const float* __restrict__ W2, const float* __restrict__ protos,
                        _Float16* __restrict__ Bsw, _Float16* __restrict__ Asw)
{
    int t0 = blockIdx.x * 256 + threadIdx.x;
    for (int idx = t0; idx < 4*8*64*8; idx += 8*256) {       // W2: kt(4) x nt(8) x lane x 8
        int j = idx & 7, l = (idx >> 3) & 63, nt = (idx >> 9) & 7, kt = idx >> 12;
        int k = kt*32 + (l >> 4)*8 + j, n = nt*16 + (l & 15);
        Bsw[idx] = (_Float16)W2[k*HID + n];
    }
    for (int idx = t0; idx < 2*4*64*8; idx += 8*256) {       // protos: mt(2) x kt(4) x lane x 8
        int j = idx & 7, l = (idx >> 3) & 63, kt = (idx >> 9) & 3, mt = idx >> 11;
        int k = kt*32 + (l >> 4)*8 + j, mm = mt*16 + (l & 15);
        Asw[idx] = (mm < NN) ? (_Float16)protos[mm*HID + k] : (_Float16)0.0f;
    }
}

// ---------------- Kernel 1: features + MLP(MFMA) + scores(MFMA) -> P into d_out ----------------
// block = 128 threads = 2 waves; wave w owns M-tile w (rows w*16..w*16+15) of both GEMMs.
// History: R2 cap84 spill; R3 cap128+full-unroll spill; R4 unroll1 -> 772us VALU-bound (W2 8x
// re-read, 4096 FMA/thread); R5 reg-dbuf defeated by scheduler. R6: MFMA rewrite (f16 operands,
// fp32 acc): 40 MFMA/wave replaces ~4900 FMA/thread, W2 traffic/block 512KB -> 64KB.
// R7 (this round): LDS lifetime union. sA (P0-P1), sH1 (P2-P3), sH (P4-P5) have disjoint
// lifetimes: sA dies at the P1->P2 barrier; sH1 is consumed into af[] registers at P3 entry and
// P4 overwrites only the writing wave's OWN 16 rows (DS ops are in-order per wave; the other
// wave reads those rows only after the pre-P5 barrier). LDS 20992 -> ~9216 B lifts the
// occupancy cap 7 -> 16 blocks/CU (the kernel was LDS-occupancy-bound: VALUBusy 44% @ 39.5% occ).
__global__ __launch_bounds__(128, 8) void k1_mlp(
    const float* __restrict__ A, const float* __restrict__ m,
    const float* __restrict__ tau_r,
    const float* __restrict__ ln1g, const float* __restrict__ ln1b,
    const float* __restrict__ W1, const float* __restrict__ b1,
    const float* __restrict__ b2,
    const float* __restrict__ ln2g, const float* __restrict__ ln2b,
    const _Float16* __restrict__ Bsw, const _Float16* __restrict__ Asw,
    float* __restrict__ out)
{
    __shared__ __align__(16) _Float16 sBuf[32 * H1S];          // 8704 B union buffer
    __shared__ __align__(16) float    sFeat[NN*4 + 4];

    float*    sA  = (float*)sBuf;      // 729 f32 = 2916 B, live P0..P1
    _Float16* sH1 = sBuf;              // h1 f16, rows 27..31 zero, live P2..P3
    _Float16* sH  = sBuf;              // normalized H f16, live P4..P5

    const int b   = blockIdx.x;
    const int tid = threadIdx.x;
    const int l = tid & 63, w = tid >> 6;
    const int c = l & 15, g = l >> 4;
    const float* Ab = A + (size_t)b * (NN * NN);

    // ---- P0: stage A ----
    for (int i = tid; i < NN * NN; i += 128) sA[i] = Ab[i];
    __syncthreads();

    // ---- P1: features [log1p(rowsum), top1_offdiag, top2_offdiag, m] + LN1 ----
    if (tid < NN) {
        const int n = tid;
        float sum = 0.f, m1 = -1e30f, m2 = -1e30f;
        #pragma unroll
        for (int j = 0; j < NN; ++j) {
            float a = sA[n * NN + j];
            sum += a;
            float v = (j == n) ? 0.f : a;
            float nm1 = fmaxf(m1, v);
            m2 = fmaxf(m2, fminf(m1, v));
            m1 = nm1;
        }
        float f0 = log1pf(sum), f1 = m1, f2 = m2, f3 = m[(size_t)b * NN + n];
        float mu = 0.25f * (f0 + f1 + f2 + f3);
        float d0 = f0 - mu, d1 = f1 - mu, d2 = f2 - mu, d3 = f3 - mu;
        float var = 0.25f * (d0*d0 + d1*d1 + d2*d2 + d3*d3);
        float rs  = rsqrtf(var + 1e-5f);
        sFeat[n*4 + 0] = d0 * rs * ln1g[0] + ln1b[0];
        sFeat[n*4 + 1] = d1 * rs * ln1g[1] + ln1b[1];
        sFeat[n*4 + 2] = d2 * rs * ln1g[2] + ln1b[2];
        sFeat[n*4 + 3] = d3 * rs * ln1g[3] + ln1b[3];
    }
    __syncthreads();

    // ---- P2: h1 = relu(featLN @ W1 + b1) -> sH1 as f16; zero pad rows 27..31 ----
    // (overwrites the dead sA region; barrier above orders P1's sA reads before these writes)
    {
        const float w0 = W1[tid], w1 = W1[HID + tid], w2 = W1[2*HID + tid], w3 = W1[3*HID + tid];
        const float bb = b1[tid];
        #pragma unroll 9
        for (int n = 0; n < NN; ++n) {
            v4 f = *(const v4*)&sFeat[n * 4];
            float v = fmaf(f[0], w0, fmaf(f[1], w1, fmaf(f[2], w2, fmaf(f[3], w3, bb))));
            sH1[n * H1S + tid] = (_Float16)fmaxf(v, 0.f);
        }
        #pragma unroll
        for (int n = NN; n < 32; ++n) sH1[n * H1S + tid] = (_Float16)0.f;
    }
    __syncthreads();

    // ---- P3: h2 = h1 @ W2 + b2 via MFMA. Wave w: rows w*16..+15, all 8 col-tiles. ----
    f16x8 af[4];
    #pragma unroll
    for (int kt = 0; kt < 4; ++kt)
        af[kt] = *(const f16x8*)&sH1[(w*16 + c) * H1S + kt*32 + g*8];

    v4 acc[8];
    #pragma unroll
    for (int nt = 0; nt < 8; ++nt) acc[nt] = (v4)(0.f);

    {
        const f16x8* Bv = (const f16x8*)Bsw;
        #pragma unroll 1            // bound live B-frags to one kt (32 regs) -> no spill
        for (int kt = 0; kt < 4; ++kt) {
            #pragma unroll
            for (int nt = 0; nt < 8; ++nt) {
                f16x8 bf = Bv[(kt*8 + nt)*64 + l];
                acc[nt] = __builtin_amdgcn_mfma_f32_16x16x32_f16(af[kt], bf, acc[nt], 0, 0, 0);
            }
        }
    }

    // ---- P4: +bias, LN2 in C-layout (lane: rows w*16+4g+r, col nt*16+c), shfl over 16 lanes ----
    // Writes only this wave's own rows of the union buffer (safe aliasing with sH1: this wave's
    // af[] reads precede in program order; other wave's reads wait at the pre-P5 barrier).
    {
        float b2v[8], g2v[8], bbv[8];
        #pragma unroll
        for (int nt = 0; nt < 8; ++nt) {
            int col = nt*16 + c;
            b2v[nt] = b2[col]; g2v[nt] = ln2g[col]; bbv[nt] = ln2b[col];
        }
        #pragma unroll
        for (int r = 0; r < 4; ++r) {
            float s = 0.f, ss = 0.f;
            #pragma unroll
            for (int nt = 0; nt < 8; ++nt) {
                float v = acc[nt][r] + b2v[nt];
                acc[nt][r] = v;
                s += v; ss += v * v;
            }
            #pragma unroll
            for (int mask = 1; mask <= 8; mask <<= 1) {
                s  += __shfl_xor(s,  mask);
                ss += __shfl_xor(ss, mask);
            }
            float mu  = s * (1.0f / HID);
            float var = ss * (1.0f / HID) - mu * mu;
            float rs  = rsqrtf(var + 1e-5f);
            int row = w*16 + 4*g + r;
            #pragma unroll
            for (int nt = 0; nt < 8; ++nt) {
                float hv = (acc[nt][r] - mu) * rs * g2v[nt] + bbv[nt];
                sH[row * H1S + nt*16 + c] = (_Float16)hv;
            }
        }
    }
    __syncthreads();   // all H rows written (both waves) before P5 B-frag reads

    // ---- P5: out[i][j] = exp((protos[i] . H[j]) / tau) via MFMA. Wave w: i-tile w. ----
    {
        const f16x8* Av = (const f16x8*)Asw;
        f16x8 pa[4];
        #pragma unroll
        for (int kt = 0; kt < 4; ++kt) pa[kt] = Av[(w*4 + kt)*64 + l];

        v4 acc2[2];
        acc2[0] = (v4)(0.f); acc2[1] = (v4)(0.f);
        #pragma unroll
        for (int kt = 0; kt < 4; ++kt) {
            f16x8 b0 = *(const f16x8*)&sH[(c)      * H1S + kt*32 + g*8];
            f16x8 b1f = *(const f16x8*)&sH[(16 + c) * H1S + kt*32 + g*8];
            acc2[0] = __builtin_amdgcn_mfma_f32_16x16x32_f16(pa[kt], b0,  acc2[0], 0, 0, 0);
            acc2[1] = __builtin_amdgcn_mfma_f32_16x16x32_f16(pa[kt], b1f, acc2[1], 0, 0, 0);
        }

        const float inv_tau = 1.0f / tau_r[0];
        float* ob = out + (size_t)b * (NN * NN);
        #pragma unroll
        for (int nt2 = 0; nt2 < 2; ++nt2) {
            int j = nt2*16 + c;
            if (j < NN) {
                #pragma unroll
                for (int r = 0; r < 4; ++r) {
                    int i = w*16 + 4*g + r;
                    if (i < NN) ob[i * NN + j] = __expf(acc2[nt2][r] * inv_tau);
                }
            }
        }
    }
}

// ---------------- Kernel 2: LINEAR-domain Sinkhorn (20 iters), in-place on P ----------------
#define ES 800   // element stride in LDS floats: 27 rows x 28 + c[28] at offset 756
__global__ __launch_bounds__(256) void k2_sinkhorn(float* __restrict__ la, int B)
{
    __shared__ __align__(16) float sLa[8 * ES];

    const int w = threadIdx.x >> 6;
    const int l = threadIdx.x & 63;
    const int half = l >> 5, r = l & 31;
    const int eb = blockIdx.x * 8 + w * 2;
    if (eb >= B) return;
    const int nel = (B - eb >= 2) ? 2 : 1;

    float* sw = sLa + (w * 2) * ES;
    const size_t gbase = (size_t)eb * (NN * NN);

    for (int idx = l; idx < nel * NN * NN; idx += 64) {
        int e = (idx >= NN * NN) ? 1 : 0;
        int p = idx - e * (NN * NN);
        int row = p / NN, col = p - row * NN;
        sw[e * ES + row * 28 + col] = la[gbase + idx];
    }
    for (int idx = l; idx < nel * 28; idx += 64) {
        int e = (idx >= 28) ? 1 : 0;
        int j = idx - e * 28;
        sw[e * ES + 756 + j] = 1.f;
        if (j < NN) sw[e * ES + j * 28 + NN] = 0.f;
    }
    __builtin_amdgcn_wave_barrier();

    float* se = sw + half * ES;
    float* ce = se + 756;
    const bool act = (r < NN) && (half < nel);

    for (int it = 0; it < SITERS; ++it) {
        if (act) {
            float* rp = se + r * 28;
            v4 x[7], cc[7];
            #pragma unroll
            for (int qi = 0; qi < 7; ++qi) { x[qi] = *(const v4*)&rp[qi * 4]; cc[qi] = *(const v4*)&ce[qi * 4]; }
            #pragma unroll
            for (int qi = 0; qi < 7; ++qi) x[qi] *= cc[qi];
            float s = 0.f;
            #pragma unroll
            for (int qi = 0; qi < 6; ++qi) s += x[qi][0] + x[qi][1] + x[qi][2] + x[qi][3];
            s += x[6][0] + x[6][1] + x[6][2];
            float rho = 1.0f / s;
            #pragma unroll
            for (int qi = 0; qi < 7; ++qi) *(v4*)&rp[qi * 4] = x[qi] * rho;
        }
        __builtin_amdgcn_wave_barrier();
        if (act) {
            const float* cp = se + r;
            float s = 0.f;
            #pragma unroll
            for (int i = 0; i < NN; ++i) s += cp[i * 28];
            ce[r] = 1.0f / s;
        }
        __builtin_amdgcn_wave_barrier();
    }

    for (int idx = l; idx < nel * NN * NN; idx += 64) {
        int e = (idx >= NN * NN) ? 1 : 0;
        int p = idx - e * (NN * NN);
        int row = p / NN, col = p - row * NN;
        la[gbase + idx] = sw[e * ES + row * 28 + col] * sw[e * ES + 756 + col];
    }
}

extern "C" void kernel_launch(void* const* d_in, const int* in_sizes, int n_in,
                              void* d_out, int out_size, void* d_ws, size_t ws_size,
                              hipStream_t stream) {
    const float* A      = (const float*)d_in[0];
    const float* m      = (const float*)d_in[1];
    const float* tau_r  = (const float*)d_in[2];
    const float* ln1g   = (const float*)d_in[3];
    const float* ln1b   = (const float*)d_in[4];
    const float* W1     = (const float*)d_in[5];
    const float* b1     = (const float*)d_in[6];
    const float* W2     = (const float*)d_in[7];
    const float* b2     = (const float*)d_in[8];
    const float* ln2g   = (const float*)d_in[9];
    const float* ln2b   = (const float*)d_in[10];
    const float* protos = (const float*)d_in[11];
    float* out = (float*)d_out;

    const int B = in_sizes[0] / (NN * NN);

    _Float16* Bsw = (_Float16*)d_ws;                         // 16384 f16 = 32 KB
    _Float16* Asw = (_Float16*)((char*)d_ws + 32768);        //  4096 f16 =  8 KB

    k0_prep<<<8, 256, 0, stream>>>(W2, protos, Bsw, Asw);
    k1_mlp<<<B, 128, 0, stream>>>(A, m, tau_r, ln1g, ln1b, W1, b1, b2,
                                  ln2g, ln2b, Bsw, Asw, out);
    const int blocks2 = (B + 7) / 8;
    k2_sinkhorn<<<blocks2, 256, 0, stream>>>(out, B);
}

// Round 2
// 669.037 us; speedup vs baseline: 1.0657x; 1.0110x over previous
//
#include <hip/hip_runtime.h>
#include <math.h>

#define NN 27
#define HID 128
#define SITERS 20
#define H1S 136          // f16 row stride for h1/H in LDS (272 B = 16B-aligned, bank-spread)

typedef float    v4    __attribute__((ext_vector_type(4)));
typedef _Float16 f16x8 __attribute__((ext_vector_type(8)));

// ---------------- Kernel 0: pre-swizzle W2 / protos into f16 MFMA fragment order ----------------
// B-frag (16x16x32): lane l holds B[k=kt*32+(l>>4)*8+j][n=nt*16+(l&15)], j=0..7 -> one 16B load/lane.
// A-frag:            lane l holds A[m=mt*16+(l&15)][k=kt*32+(l>>4)*8+j]          (m120-verified layout)
__global__ void k0_prep(const float* __restrict__ W2, const float* __restrict__ protos,
                        _Float16* __restrict__ Bsw, _Float16* __restrict__ Asw)
{
    int t0 = blockIdx.x * 256 + threadIdx.x;
    for (int idx = t0; idx < 4*8*64*8; idx += 8*256) {       // W2: kt(4) x nt(8) x lane x 8
        int j = idx & 7, l = (idx >> 3) & 63, nt = (idx >> 9) & 7, kt = idx >> 12;
        int k = kt*32 + (l >> 4)*8 + j, n = nt*16 + (l & 15);
        Bsw[idx] = (_Float16)W2[k*HID + n];
    }
    for (int idx = t0; idx < 2*4*64*8; idx += 8*256) {       // protos: mt(2) x kt(4) x lane x 8
        int j = idx & 7, l = (idx >> 3) & 63, kt = (idx >> 9) & 3, mt = idx >> 11;
        int k = kt*32 + (l >> 4)*8 + j, mm = mt*16 + (l & 15);
        Asw[idx] = (mm < NN) ? (_Float16)protos[mm*HID + k] : (_Float16)0.0f;
    }
}

// ---------------- Kernel 1: features + MLP(MFMA) + scores(MFMA) + SINKHORN, fully fused ----------
// block = 128 threads = 2 waves; wave w owns M-tile w (rows w*16..w*16+15) of both GEMMs.
// History: R6 MFMA rewrite; R7 LDS lifetime union (20992->9216 B, occ 39.5->88%, 474->432us,
// VALUBusy only 51% -> latency-limited, not issue-limited). R8 (this round): fuse Sinkhorn.
// k2 was ~240us: a 95MB P read + 95MB write round-trip plus a latency-chained LDS loop at low
// utilization, while k1 idles 49% of issue slots. P never leaves the block now: P5 writes
// exp(score/tau) into the union buffer (k2's 27x28+ce layout), wave 0 runs the 20-iter
// linear-domain Sinkhorn (wave_barrier-synced, lanes 0..26), both waves write out contiguously
// (also kills the 6x L2 partial-line write amplification P5's scattered stores caused).
__global__ __launch_bounds__(128, 8) void k1_mlp(
    const float* __restrict__ A, const float* __restrict__ m,
    const float* __restrict__ tau_r,
    const float* __restrict__ ln1g, const float* __restrict__ ln1b,
    const float* __restrict__ W1, const float* __restrict__ b1,
    const float* __restrict__ b2,
    const float* __restrict__ ln2g, const float* __restrict__ ln2b,
    const _Float16* __restrict__ Bsw, const _Float16* __restrict__ Asw,
    float* __restrict__ out)
{
    __shared__ __align__(16) _Float16 sBuf[32 * H1S];          // 8704 B union buffer
    __shared__ __align__(16) float    sFeat[NN*4 + 4];

    float*    sA  = (float*)sBuf;      // 729 f32 = 2916 B, live P0..P1
    _Float16* sH1 = sBuf;              // h1 f16, rows 27..31 zero, live P2..P3
    _Float16* sH  = sBuf;              // normalized H f16, live P4..P5
    float*    sS  = (float*)sBuf;      // Sinkhorn 27x28 + ce[28] @756 = 784 f32, live P6..P8

    const int b   = blockIdx.x;
    const int tid = threadIdx.x;
    const int l = tid & 63, w = tid >> 6;
    const int c = l & 15, g = l >> 4;
    const float* Ab = A + (size_t)b * (NN * NN);

    // ---- P0: stage A ----
    for (int i = tid; i < NN * NN; i += 128) sA[i] = Ab[i];
    __syncthreads();

    // ---- P1: features [log1p(rowsum), top1_offdiag, top2_offdiag, m] + LN1 ----
    if (tid < NN) {
        const int n = tid;
        float sum = 0.f, m1 = -1e30f, m2 = -1e30f;
        #pragma unroll
        for (int j = 0; j < NN; ++j) {
            float a = sA[n * NN + j];
            sum += a;
            float v = (j == n) ? 0.f : a;
            float nm1 = fmaxf(m1, v);
            m2 = fmaxf(m2, fminf(m1, v));
            m1 = nm1;
        }
        float f0 = log1pf(sum), f1 = m1, f2 = m2, f3 = m[(size_t)b * NN + n];
        float mu = 0.25f * (f0 + f1 + f2 + f3);
        float d0 = f0 - mu, d1 = f1 - mu, d2 = f2 - mu, d3 = f3 - mu;
        float var = 0.25f * (d0*d0 + d1*d1 + d2*d2 + d3*d3);
        float rs  = rsqrtf(var + 1e-5f);
        sFeat[n*4 + 0] = d0 * rs * ln1g[0] + ln1b[0];
        sFeat[n*4 + 1] = d1 * rs * ln1g[1] + ln1b[1];
        sFeat[n*4 + 2] = d2 * rs * ln1g[2] + ln1b[2];
        sFeat[n*4 + 3] = d3 * rs * ln1g[3] + ln1b[3];
    }
    __syncthreads();

    // ---- P2: h1 = relu(featLN @ W1 + b1) -> sH1 as f16; zero pad rows 27..31 ----
    {
        const float w0 = W1[tid], w1 = W1[HID + tid], w2 = W1[2*HID + tid], w3 = W1[3*HID + tid];
        const float bb = b1[tid];
        #pragma unroll 9
        for (int n = 0; n < NN; ++n) {
            v4 f = *(const v4*)&sFeat[n * 4];
            float v = fmaf(f[0], w0, fmaf(f[1], w1, fmaf(f[2], w2, fmaf(f[3], w3, bb))));
            sH1[n * H1S + tid] = (_Float16)fmaxf(v, 0.f);
        }
        #pragma unroll
        for (int n = NN; n < 32; ++n) sH1[n * H1S + tid] = (_Float16)0.f;
    }
    __syncthreads();

    // ---- P3: h2 = h1 @ W2 + b2 via MFMA. Wave w: rows w*16..+15, all 8 col-tiles. ----
    f16x8 af[4];
    #pragma unroll
    for (int kt = 0; kt < 4; ++kt)
        af[kt] = *(const f16x8*)&sH1[(w*16 + c) * H1S + kt*32 + g*8];

    v4 acc[8];
    #pragma unroll
    for (int nt = 0; nt < 8; ++nt) acc[nt] = (v4)(0.f);

    {
        const f16x8* Bv = (const f16x8*)Bsw;
        #pragma unroll 1            // bound live B-frags to one kt (32 regs) -> no spill
        for (int kt = 0; kt < 4; ++kt) {
            #pragma unroll
            for (int nt = 0; nt < 8; ++nt) {
                f16x8 bf = Bv[(kt*8 + nt)*64 + l];
                acc[nt] = __builtin_amdgcn_mfma_f32_16x16x32_f16(af[kt], bf, acc[nt], 0, 0, 0);
            }
        }
    }

    // ---- P4: +bias, LN2 in C-layout (lane: rows w*16+4g+r, col nt*16+c), shfl over 16 lanes ----
    {
        float b2v[8], g2v[8], bbv[8];
        #pragma unroll
        for (int nt = 0; nt < 8; ++nt) {
            int col = nt*16 + c;
            b2v[nt] = b2[col]; g2v[nt] = ln2g[col]; bbv[nt] = ln2b[col];
        }
        #pragma unroll
        for (int r = 0; r < 4; ++r) {
            float s = 0.f, ss = 0.f;
            #pragma unroll
            for (int nt = 0; nt < 8; ++nt) {
                float v = acc[nt][r] + b2v[nt];
                acc[nt][r] = v;
                s += v; ss += v * v;
            }
            #pragma unroll
            for (int mask = 1; mask <= 8; mask <<= 1) {
                s  += __shfl_xor(s,  mask);
                ss += __shfl_xor(ss, mask);
            }
            float mu  = s * (1.0f / HID);
            float var = ss * (1.0f / HID) - mu * mu;
            float rs  = rsqrtf(var + 1e-5f);
            int row = w*16 + 4*g + r;
            #pragma unroll
            for (int nt = 0; nt < 8; ++nt) {
                float hv = (acc[nt][r] - mu) * rs * g2v[nt] + bbv[nt];
                sH[row * H1S + nt*16 + c] = (_Float16)hv;
            }
        }
    }
    __syncthreads();   // all H rows written (both waves) before P5 B-frag reads

    // ---- P5: scores[i][j] = protos[i] . H[j] via MFMA. Wave w: i-tile w. ----
    v4 acc2[2];
    {
        const f16x8* Av = (const f16x8*)Asw;
        f16x8 pa[4];
        #pragma unroll
        for (int kt = 0; kt < 4; ++kt) pa[kt] = Av[(w*4 + kt)*64 + l];

        acc2[0] = (v4)(0.f); acc2[1] = (v4)(0.f);
        #pragma unroll
        for (int kt = 0; kt < 4; ++kt) {
            f16x8 b0  = *(const f16x8*)&sH[(c)      * H1S + kt*32 + g*8];
            f16x8 b1f = *(const f16x8*)&sH[(16 + c) * H1S + kt*32 + g*8];
            acc2[0] = __builtin_amdgcn_mfma_f32_16x16x32_f16(pa[kt], b0,  acc2[0], 0, 0, 0);
            acc2[1] = __builtin_amdgcn_mfma_f32_16x16x32_f16(pa[kt], b1f, acc2[1], 0, 0, 0);
        }
    }
    __syncthreads();   // both waves' sH reads complete before sS overwrites the union buffer

    // ---- P6: P = exp(score/tau) -> sS (k2 layout: row*28+col, ce[28] @756, col 27 = 0) ----
    {
        const float inv_tau = 1.0f / tau_r[0];
        #pragma unroll
        for (int nt2 = 0; nt2 < 2; ++nt2) {
            int j = nt2*16 + c;
            if (j < NN) {
                #pragma unroll
                for (int r = 0; r < 4; ++r) {
                    int i = w*16 + 4*g + r;
                    if (i < NN) sS[i*28 + j] = __expf(acc2[nt2][r] * inv_tau);
                }
            }
        }
        if (tid < 28) sS[756 + tid] = 1.f;     // ce init (ce[27] stays 1 forever)
        if (tid < NN) sS[tid*28 + NN] = 0.f;   // pad col 27 = 0 (stays 0: scaled each iter)
    }
    __syncthreads();

    // ---- P7: 20-iter linear-domain Sinkhorn, wave 0 only, lanes 0..26, wave_barrier sync ----
    // Two-pass row phase (sum, then re-read+rescale with a compiler memory fence between)
    // keeps live registers ~2 v4s so VGPR stays under the 64-reg / 8-waves-per-EU budget.
    if (w == 0) {
        float* ce = sS + 756;
        const bool act = (l < NN);
        for (int it = 0; it < SITERS; ++it) {
            if (act) {
                float* rp = sS + l * 28;
                float s = 0.f;
                #pragma unroll
                for (int qi = 0; qi < 7; ++qi) {
                    v4 x  = *(const v4*)&rp[qi * 4];
                    v4 cv = *(const v4*)&ce[qi * 4];
                    v4 p  = x * cv;
                    s += p[0] + p[1] + p[2] + p[3];   // word 27 contributes 0*1
                }
                float rho = 1.0f / s;
                asm volatile("" ::: "memory");        // force re-read: cap live VGPRs
                #pragma unroll
                for (int qi = 0; qi < 7; ++qi) {
                    v4 x  = *(const v4*)&rp[qi * 4];
                    v4 cv = *(const v4*)&ce[qi * 4];
                    *(v4*)&rp[qi * 4] = x * cv * rho;
                }
            }
            __builtin_amdgcn_wave_barrier();
            if (act) {
                const float* cp = sS + l;
                float s2 = 0.f;
                #pragma unroll
                for (int i2 = 0; i2 < NN; ++i2) s2 += cp[i2 * 28];
                ce[l] = 1.0f / s2;
            }
            __builtin_amdgcn_wave_barrier();
        }
    }
    __syncthreads();

    // ---- P8: out = row * ce[col], contiguous coalesced write (one pass, full lines) ----
    {
        float* ob = out + (size_t)b * (NN * NN);
        for (int idx = tid; idx < NN * NN; idx += 128) {
            int row = idx / NN, col = idx - row * NN;
            ob[idx] = sS[row * 28 + col] * sS[756 + col];
        }
    }
}

extern "C" void kernel_launch(void* const* d_in, const int* in_sizes, int n_in,
                              void* d_out, int out_size, void* d_ws, size_t ws_size,
                              hipStream_t stream) {
    const float* A      = (const float*)d_in[0];
    const float* m      = (const float*)d_in[1];
    const float* tau_r  = (const float*)d_in[2];
    const float* ln1g   = (const float*)d_in[3];
    const float* ln1b   = (const float*)d_in[4];
    const float* W1     = (const float*)d_in[5];
    const float* b1     = (const float*)d_in[6];
    const float* W2     = (const float*)d_in[7];
    const float* b2     = (const float*)d_in[8];
    const float* ln2g   = (const float*)d_in[9];
    const float* ln2b   = (const float*)d_in[10];
    const float* protos = (const float*)d_in[11];
    float* out = (float*)d_out;

    const int B = in_sizes[0] / (NN * NN);

    _Float16* Bsw = (_Float16*)d_ws;                         // 16384 f16 = 32 KB
    _Float16* Asw = (_Float16*)((char*)d_ws + 32768);        //  4096 f16 =  8 KB

    k0_prep<<<8, 256, 0, stream>>>(W2, protos, Bsw, Asw);
    k1_mlp<<<B, 128, 0, stream>>>(A, m, tau_r, ln1g, ln1b, W1, b1, b2,
                                  ln2g, ln2b, Bsw, Asw, out);
}

// Round 3
// 562.435 us; speedup vs baseline: 1.2677x; 1.1895x over previous
//
#include <hip/hip_runtime.h>
#include <math.h>

#define NN 27
#define HID 128
#define SITERS 20
#define H1S 136          // f16 row stride for h1/H in LDS (272 B = 16B-aligned, bank-spread)

typedef float    v4    __attribute__((ext_vector_type(4)));
typedef _Float16 f16x8 __attribute__((ext_vector_type(8)));

// ---------------- Kernel 0: pre-swizzle W2 / protos into f16 MFMA fragment order ----------------
// B-frag (16x16x32): lane l holds B[k=kt*32+(l>>4)*8+j][n=nt*16+(l&15)], j=0..7 -> one 16B load/lane.
// A-frag:            lane l holds A[m=mt*16+(l&15)][k=kt*32+(l>>4)*8+j]          (m120-verified layout)
__global__ void k0_prep(const float* __restrict__ W2, const float* __restrict__ protos,
                        _Float16* __restrict__ Bsw, _Float16* __restrict__ Asw)
{
    int t0 = blockIdx.x * 256 + threadIdx.x;
    for (int idx = t0; idx < 4*8*64*8; idx += 8*256) {       // W2: kt(4) x nt(8) x lane x 8
        int j = idx & 7, l = (idx >> 3) & 63, nt = (idx >> 9) & 7, kt = idx >> 12;
        int k = kt*32 + (l >> 4)*8 + j, n = nt*16 + (l & 15);
        Bsw[idx] = (_Float16)W2[k*HID + n];
    }
    for (int idx = t0; idx < 2*4*64*8; idx += 8*256) {       // protos: mt(2) x kt(4) x lane x 8
        int j = idx & 7, l = (idx >> 3) & 63, kt = (idx >> 9) & 3, mt = idx >> 11;
        int k = kt*32 + (l >> 4)*8 + j, mm = mt*16 + (l & 15);
        Asw[idx] = (mm < NN) ? (_Float16)protos[mm*HID + k] : (_Float16)0.0f;
    }
}

// ---------------- Kernel 1: features + MLP(MFMA) + scores(MFMA) + SINKHORN, fully fused ----------
// block = 128 threads = 2 waves; wave w owns M-tile w (rows w*16..w*16+15) of both GEMMs.
// History: R6 MFMA rewrite; R7 LDS union (occ 39.5->88%); R8 Sinkhorn fusion (k2's 190MB HBM
// round-trip deleted, but k1 592us). R9 (this round): DESPILL. R7's launch_bounds(128,8) caps
// the unified VGPR+AGPR file at 64/lane; the old P3/P4 (acc[8]=32 + af[4]=16 + 24 coef regs)
// needed ~90 -> ~500MB of scratch writes + ~160MB reloads per dispatch (WRITE_SIZE 624MB vs
// 95.5MB true output). Fix: loop-interchange GEMM2 (one 4-reg acc tile) + TWO-PASS MFMA:
// pass1 accumulates LN2 s/ss only (tiles discarded), pass2 recomputes bit-identical tiles and
// fuses bias+LN2+f16 store. 32 extra MFMA/wave (3%-busy pipe) buys removal of the scratch
// round-trip. Arithmetic order identical to R8 -> absmax unchanged.
__global__ __launch_bounds__(128, 8) void k1_mlp(
    const float* __restrict__ A, const float* __restrict__ m,
    const float* __restrict__ tau_r,
    const float* __restrict__ ln1g, const float* __restrict__ ln1b,
    const float* __restrict__ W1, const float* __restrict__ b1,
    const float* __restrict__ b2,
    const float* __restrict__ ln2g, const float* __restrict__ ln2b,
    const _Float16* __restrict__ Bsw, const _Float16* __restrict__ Asw,
    float* __restrict__ out)
{
    __shared__ __align__(16) _Float16 sBuf[32 * H1S];          // 8704 B union buffer
    __shared__ __align__(16) float    sFeat[NN*4 + 4];

    float*    sA  = (float*)sBuf;      // 729 f32 = 2916 B, live P0..P1
    _Float16* sH1 = sBuf;              // h1 f16, rows 27..31 zero, live P2..P3
    _Float16* sH  = sBuf;              // normalized H f16, live P3b..P5
    float*    sS  = (float*)sBuf;      // Sinkhorn 27x28 + ce[28] @756 = 784 f32, live P6..P8

    const int b   = blockIdx.x;
    const int tid = threadIdx.x;
    const int l = tid & 63, w = tid >> 6;
    const int c = l & 15, g = l >> 4;
    const float* Ab = A + (size_t)b * (NN * NN);

    // ---- P0: stage A ----
    for (int i = tid; i < NN * NN; i += 128) sA[i] = Ab[i];
    __syncthreads();

    // ---- P1: features [log1p(rowsum), top1_offdiag, top2_offdiag, m] + LN1 ----
    if (tid < NN) {
        const int n = tid;
        float sum = 0.f, m1 = -1e30f, m2 = -1e30f;
        #pragma unroll
        for (int j = 0; j < NN; ++j) {
            float a = sA[n * NN + j];
            sum += a;
            float v = (j == n) ? 0.f : a;
            float nm1 = fmaxf(m1, v);
            m2 = fmaxf(m2, fminf(m1, v));
            m1 = nm1;
        }
        float f0 = log1pf(sum), f1 = m1, f2 = m2, f3 = m[(size_t)b * NN + n];
        float mu = 0.25f * (f0 + f1 + f2 + f3);
        float d0 = f0 - mu, d1 = f1 - mu, d2 = f2 - mu, d3 = f3 - mu;
        float var = 0.25f * (d0*d0 + d1*d1 + d2*d2 + d3*d3);
        float rs  = rsqrtf(var + 1e-5f);
        sFeat[n*4 + 0] = d0 * rs * ln1g[0] + ln1b[0];
        sFeat[n*4 + 1] = d1 * rs * ln1g[1] + ln1b[1];
        sFeat[n*4 + 2] = d2 * rs * ln1g[2] + ln1b[2];
        sFeat[n*4 + 3] = d3 * rs * ln1g[3] + ln1b[3];
    }
    __syncthreads();

    // ---- P2: h1 = relu(featLN @ W1 + b1) -> sH1 as f16; zero pad rows 27..31 ----
    {
        const float w0 = W1[tid], w1 = W1[HID + tid], w2 = W1[2*HID + tid], w3 = W1[3*HID + tid];
        const float bb = b1[tid];
        #pragma unroll 9
        for (int n = 0; n < NN; ++n) {
            v4 f = *(const v4*)&sFeat[n * 4];
            float v = fmaf(f[0], w0, fmaf(f[1], w1, fmaf(f[2], w2, fmaf(f[3], w3, bb))));
            sH1[n * H1S + tid] = (_Float16)fmaxf(v, 0.f);
        }
        #pragma unroll
        for (int n = NN; n < 32; ++n) sH1[n * H1S + tid] = (_Float16)0.f;
    }
    __syncthreads();

    // ---- P3: GEMM2 h2 = h1@W2, two-pass. Wave w: rows w*16..+15, one acc tile live. ----
    f16x8 af[4];
    #pragma unroll
    for (int kt = 0; kt < 4; ++kt)
        af[kt] = *(const f16x8*)&sH1[(w*16 + c) * H1S + kt*32 + g*8];

    const f16x8* Bv = (const f16x8*)Bsw;

    // pass 1: LN2 stats only
    float s4[4]  = {0.f, 0.f, 0.f, 0.f};
    float ss4[4] = {0.f, 0.f, 0.f, 0.f};
    #pragma unroll 1
    for (int nt = 0; nt < 8; ++nt) {
        v4 a = (v4)(0.f);
        #pragma unroll
        for (int kt = 0; kt < 4; ++kt)
            a = __builtin_amdgcn_mfma_f32_16x16x32_f16(af[kt], Bv[(kt*8 + nt)*64 + l], a, 0, 0, 0);
        float b2v = b2[nt*16 + c];
        #pragma unroll
        for (int r = 0; r < 4; ++r) {
            float v = a[r] + b2v;
            s4[r] += v; ss4[r] += v * v;
        }
    }
    float muv[4], rsv[4];
    #pragma unroll
    for (int r = 0; r < 4; ++r) {
        #pragma unroll
        for (int mask = 1; mask <= 8; mask <<= 1) {
            s4[r]  += __shfl_xor(s4[r],  mask);
            ss4[r] += __shfl_xor(ss4[r], mask);
        }
        float mu  = s4[r] * (1.0f / HID);
        float var = ss4[r] * (1.0f / HID) - mu * mu;
        muv[r] = mu;
        rsv[r] = rsqrtf(var + 1e-5f);
    }

    // pass 2: recompute identical tiles, fuse bias + LN2, store f16 H (own rows only:
    // safe aliasing with sH1 — this wave's af[] is already in regs, other wave reads own rows)
    #pragma unroll 1
    for (int nt = 0; nt < 8; ++nt) {
        v4 a = (v4)(0.f);
        #pragma unroll
        for (int kt = 0; kt < 4; ++kt)
            a = __builtin_amdgcn_mfma_f32_16x16x32_f16(af[kt], Bv[(kt*8 + nt)*64 + l], a, 0, 0, 0);
        int col = nt*16 + c;
        float b2v = b2[col], g2 = ln2g[col], bb = ln2b[col];
        #pragma unroll
        for (int r = 0; r < 4; ++r) {
            float hv = (a[r] + b2v - muv[r]) * rsv[r] * g2 + bb;
            sH[(w*16 + 4*g + r) * H1S + col] = (_Float16)hv;
        }
    }
    __syncthreads();   // all H rows written (both waves) before P5 B-frag reads

    // ---- P5: scores[i][j] = protos[i] . H[j] via MFMA. Wave w: i-tile w. ----
    v4 acc2[2];
    {
        const f16x8* Av = (const f16x8*)Asw;
        acc2[0] = (v4)(0.f); acc2[1] = (v4)(0.f);
        #pragma unroll
        for (int kt = 0; kt < 4; ++kt) {
            f16x8 pa  = Av[(w*4 + kt)*64 + l];
            f16x8 b0  = *(const f16x8*)&sH[(c)      * H1S + kt*32 + g*8];
            f16x8 b1f = *(const f16x8*)&sH[(16 + c) * H1S + kt*32 + g*8];
            acc2[0] = __builtin_amdgcn_mfma_f32_16x16x32_f16(pa, b0,  acc2[0], 0, 0, 0);
            acc2[1] = __builtin_amdgcn_mfma_f32_16x16x32_f16(pa, b1f, acc2[1], 0, 0, 0);
        }
    }
    __syncthreads();   // both waves' sH reads complete before sS overwrites the union buffer

    // ---- P6: P = exp(score/tau) -> sS (k2 layout: row*28+col, ce[28] @756, col 27 = 0) ----
    {
        const float inv_tau = 1.0f / tau_r[0];
        #pragma unroll
        for (int nt2 = 0; nt2 < 2; ++nt2) {
            int j = nt2*16 + c;
            if (j < NN) {
                #pragma unroll
                for (int r = 0; r < 4; ++r) {
                    int i = w*16 + 4*g + r;
                    if (i < NN) sS[i*28 + j] = __expf(acc2[nt2][r] * inv_tau);
                }
            }
        }
        if (tid < 28) sS[756 + tid] = 1.f;     // ce init (ce[27] stays 1 forever)
        if (tid < NN) sS[tid*28 + NN] = 0.f;   // pad col 27 = 0 (stays 0: scaled each iter)
    }
    __syncthreads();

    // ---- P7: 20-iter linear-domain Sinkhorn, wave 0 only, lanes 0..26, wave_barrier sync ----
    // Two-pass row phase (sum, then re-read+rescale with a compiler memory fence between)
    // keeps live registers ~2 v4s — do NOT revert to the 14-v4 single-pass form (56 regs).
    if (w == 0) {
        float* ce = sS + 756;
        const bool act = (l < NN);
        for (int it = 0; it < SITERS; ++it) {
            if (act) {
                float* rp = sS + l * 28;
                float s = 0.f;
                #pragma unroll
                for (int qi = 0; qi < 7; ++qi) {
                    v4 x  = *(const v4*)&rp[qi * 4];
                    v4 cv = *(const v4*)&ce[qi * 4];
                    v4 p  = x * cv;
                    s += p[0] + p[1] + p[2] + p[3];   // word 27 contributes 0*1
                }
                float rho = 1.0f / s;
                asm volatile("" ::: "memory");        // force re-read: cap live VGPRs
                #pragma unroll
                for (int qi = 0; qi < 7; ++qi) {
                    v4 x  = *(const v4*)&rp[qi * 4];
                    v4 cv = *(const v4*)&ce[qi * 4];
                    *(v4*)&rp[qi * 4] = x * cv * rho;
                }
            }
            __builtin_amdgcn_wave_barrier();
            if (act) {
                const float* cp = sS + l;
                float s2 = 0.f;
                #pragma unroll
                for (int i2 = 0; i2 < NN; ++i2) s2 += cp[i2 * 28];
                ce[l] = 1.0f / s2;
            }
            __builtin_amdgcn_wave_barrier();
        }
    }
    __syncthreads();

    // ---- P8: out = row * ce[col], contiguous coalesced write (one pass, full lines) ----
    {
        float* ob = out + (size_t)b * (NN * NN);
        for (int idx = tid; idx < NN * NN; idx += 128) {
            int row = idx / NN, col = idx - row * NN;
            ob[idx] = sS[row * 28 + col] * sS[756 + col];
        }
    }
}

extern "C" void kernel_launch(void* const* d_in, const int* in_sizes, int n_in,
                              void* d_out, int out_size, void* d_ws, size_t ws_size,
                              hipStream_t stream) {
    const float* A      = (const float*)d_in[0];
    const float* m      = (const float*)d_in[1];
    const float* tau_r  = (const float*)d_in[2];
    const float* ln1g   = (const float*)d_in[3];
    const float* ln1b   = (const float*)d_in[4];
    const float* W1     = (const float*)d_in[5];
    const float* b1     = (const float*)d_in[6];
    const float* W2     = (const float*)d_in[7];
    const float* b2     = (const float*)d_in[8];
    const float* ln2g   = (const float*)d_in[9];
    const float* ln2b   = (const float*)d_in[10];
    const float* protos = (const float*)d_in[11];
    float* out = (float*)d_out;

    const int B = in_sizes[0] / (NN * NN);

    _Float16* Bsw = (_Float16*)d_ws;                         // 16384 f16 = 32 KB
    _Float16* Asw = (_Float16*)((char*)d_ws + 32768);        //  4096 f16 =  8 KB

    k0_prep<<<8, 256, 0, stream>>>(W2, protos, Bsw, Asw);
    k1_mlp<<<B, 128, 0, stream>>>(A, m, tau_r, ln1g, ln1b, W1, b1, b2,
                                  ln2g, ln2b, Bsw, Asw, out);
}